// Round 1
// baseline (343.664 us; speedup 1.0000x reference)
//
#include <hip/hip_runtime.h>
#include <hip/hip_bf16.h>

typedef short short8 __attribute__((ext_vector_type(8)));
typedef float floatx4 __attribute__((ext_vector_type(4)));
typedef __hip_bfloat16 bf16;

#define GLB(p) ((const __attribute__((address_space(1))) void*)(p))
#define LDSP(p) ((__attribute__((address_space(3))) void*)(p))

__device__ __forceinline__ void gload16(const bf16* g, char* l) {
    __builtin_amdgcn_global_load_lds(GLB(g), LDSP(l), 16, 0, 0);
}

// ---- problem sizes ----
// x: (64,128,56,56) f32; out: (64,256,28,28) f32
// xpad:  [64][58][58][128] bf16 (halo=1, conv1 pad baked in)
// actpad:[64][30][30][256] bf16 (halo=1 for conv2 pad)
#define XPAD_BYTES   (64u*58*58*128*2)              // 55,115,776
#define ACTPAD_BYTES (64u*30*30*256*2)              // 29,491,200
#define OFF_XPAD   0
#define OFF_ACTPAD (XPAD_BYTES)
#define OFF_W1T    (OFF_ACTPAD + ACTPAD_BYTES)      // 84,606,976
#define OFF_W2T    (OFF_W1T + 1152u*256*2)          // 85,196,800
#define OFF_WDST   (OFF_W2T + 2304u*256*2)          // 86,376,448

// ---------------- weight transforms: OIHW f32 -> [oc][k] bf16, k=(kh*3+kw)*C+ic
__global__ void wtrans_kernel(const float* __restrict__ w1, const float* __restrict__ w2,
                              const float* __restrict__ wds,
                              bf16* __restrict__ w1t, bf16* __restrict__ w2t,
                              bf16* __restrict__ wdst) {
    int i = blockIdx.x * 256 + threadIdx.x;
    if (i < 256 * 1152) {
        int oc = i / 1152, k = i % 1152, tap = k >> 7, ic = k & 127;
        w1t[i] = __float2bfloat16(w1[(oc * 128 + ic) * 9 + tap]);
    }
    if (i < 256 * 2304) {
        int oc = i / 2304, k = i % 2304, tap = k >> 8, ic = k & 255;
        w2t[i] = __float2bfloat16(w2[(oc * 256 + ic) * 9 + tap]);
    }
    if (i < 256 * 128) {
        wdst[i] = __float2bfloat16(wds[i]); // already [oc][ic]
    }
}

// ---------------- x: NCHW f32 -> xpad NHWC bf16 (interior only; halo pre-zeroed)
__global__ void xpad_kernel(const float* __restrict__ x, bf16* __restrict__ xpad) {
    int bid = blockIdx.x;             // 64*56 blocks: one (n,h) row each
    int n = bid / 56, h = bid % 56;
    __shared__ float tile[128 * 57];  // [c][w], pad stride 57 to break bank conflicts
    const float* src = x + ((size_t)n * 128) * 3136 + h * 56;
    for (int e = threadIdx.x; e < 128 * 56; e += 256) {
        int c = e / 56, w = e % 56;
        tile[c * 57 + w] = src[(size_t)c * 3136 + w];
    }
    __syncthreads();
    bf16* dst = xpad + ((size_t)(n * 58 + h + 1) * 58 + 1) * 128;
    for (int e = threadIdx.x; e < 56 * 16; e += 256) {
        int w = e / 16, g = e % 16;
        union { bf16 b[8]; uint4 v; } o;
        #pragma unroll
        for (int j = 0; j < 8; ++j)
            o.b[j] = __float2bfloat16(tile[(g * 8 + j) * 57 + w]);
        *(uint4*)(dst + (size_t)w * 128 + g * 8) = o.v;
    }
}

// ---------------- conv1: 3x3 s2 p1 + b1 + relu -> actpad (bf16, NHWC padded)
// GEMM: C[m][oc], A = x-patches (rows m), B = w1t (cols oc), K = 1152
__global__ __launch_bounds__(256) void conv1_kernel(
    const bf16* __restrict__ xpad, const bf16* __restrict__ w1t,
    const float* __restrict__ b1, bf16* __restrict__ actpad)
{
    __shared__ __align__(16) char lds[32768];  // [0,16K): A-tile [128m][64k]; [16K,32K): W-tile [128oc][64k]
    const int t = threadIdx.x;
    const int oc0 = blockIdx.x * 128;
    const int m0  = blockIdx.y * 128;

    const int srow = t >> 3, sunit = t & 7;
    const int uo = ((sunit ^ (srow & 7)) << 3);   // source-side swizzle (elements)

    size_t aeoff[4], weoff[4];
    #pragma unroll
    for (int i = 0; i < 4; ++i) {
        int r = srow + 32 * i;
        int m = m0 + r;
        int n = m / 784, pix = m % 784;
        int oh = pix / 28, ow = pix % 28;
        aeoff[i] = (size_t)((n * 58 + 2 * oh) * 58 + 2 * ow) * 128 + uo;
        weoff[i] = (size_t)(oc0 + r) * 1152 + uo;
    }
    const int ldsa0 = t * 16;
    const int ldsw0 = 16384 + t * 16;

    const int lane = t & 63, wid = t >> 6;
    const int wm = (wid >> 1) << 6, woc = (wid & 1) << 6;
    const int lrow = lane & 15, lhi = lane >> 4;
    int aoffs[4][2], woffs[4][2];
    #pragma unroll
    for (int f = 0; f < 4; ++f)
        #pragma unroll
        for (int h = 0; h < 2; ++h) {
            int ra = wm + f * 16 + lrow;
            aoffs[f][h] = ra * 128 + (((lhi + (h << 2)) ^ (ra & 7)) << 4);
            int rw = woc + f * 16 + lrow;
            woffs[f][h] = 16384 + rw * 128 + (((lhi + (h << 2)) ^ (rw & 7)) << 4);
        }

    floatx4 acc[4][4];
    #pragma unroll
    for (int a = 0; a < 4; ++a)
        #pragma unroll
        for (int b = 0; b < 4; ++b) acc[a][b] = (floatx4){0.f, 0.f, 0.f, 0.f};

    for (int s = 0; s < 18; ++s) {
        int tap = s >> 1, chunk = s & 1;
        int kh = tap / 3, kw = tap % 3;
        size_t aoff = (size_t)(kh * 58 + kw) * 128 + chunk * 64;
        size_t woff = (size_t)s * 64;
        #pragma unroll
        for (int i = 0; i < 4; ++i) gload16(xpad + aeoff[i] + aoff, lds + ldsa0 + i * 4096);
        #pragma unroll
        for (int i = 0; i < 4; ++i) gload16(w1t + weoff[i] + woff, lds + ldsw0 + i * 4096);
        __syncthreads();
        #pragma unroll
        for (int h = 0; h < 2; ++h) {
            short8 af[4], wf[4];
            #pragma unroll
            for (int f = 0; f < 4; ++f) af[f] = *(const short8*)(lds + aoffs[f][h]);
            #pragma unroll
            for (int f = 0; f < 4; ++f) wf[f] = *(const short8*)(lds + woffs[f][h]);
            #pragma unroll
            for (int fm = 0; fm < 4; ++fm)
                #pragma unroll
                for (int fo = 0; fo < 4; ++fo)
                    acc[fm][fo] = __builtin_amdgcn_mfma_f32_16x16x32_bf16(af[fm], wf[fo], acc[fm][fo], 0, 0, 0);
        }
        __syncthreads();
    }

    // epilogue: D rows = m ((lane>>4)*4+reg), cols = oc (lane&15)
    #pragma unroll
    for (int fm = 0; fm < 4; ++fm) {
        #pragma unroll
        for (int rg = 0; rg < 4; ++rg) {
            int m = m0 + wm + fm * 16 + (lhi << 2) + rg;
            int n = m / 784, pix = m % 784;
            int oh = pix / 28, ow = pix % 28;
            bf16* dst = actpad + ((size_t)(n * 30 + oh + 1) * 30 + (ow + 1)) * 256;
            #pragma unroll
            for (int fo = 0; fo < 4; ++fo) {
                int oc = oc0 + woc + fo * 16 + lrow;
                float v = acc[fm][fo][rg] + b1[oc];
                dst[oc] = __float2bfloat16(fmaxf(v, 0.0f));
            }
        }
    }
}

// ---------------- conv2: 3x3 s1 p1 over actpad + b2 + (1x1 s2 shortcut + bds) + relu -> out NCHW f32
// GEMM: C[oc][m], A = w2t (rows oc), B = act-patches (cols m), K = 2304 + 128
__global__ __launch_bounds__(256) void conv2_kernel(
    const bf16* __restrict__ actpad, const bf16* __restrict__ xpad,
    const bf16* __restrict__ w2t, const bf16* __restrict__ wdst,
    const float* __restrict__ b2, const float* __restrict__ bds,
    float* __restrict__ out)
{
    __shared__ __align__(16) char lds[32768];
    const int t = threadIdx.x;
    const int oc0 = blockIdx.x * 128;
    const int m0  = blockIdx.y * 128;

    const int srow = t >> 3, sunit = t & 7;
    const int uo = ((sunit ^ (srow & 7)) << 3);

    size_t aeoff[4], weoff[4];
    int pk[4];
    #pragma unroll
    for (int i = 0; i < 4; ++i) {
        int r = srow + 32 * i;
        int m = m0 + r;
        int n = m / 784, pix = m % 784;
        int oh = pix / 28, ow = pix % 28;
        pk[i] = (n << 10) | (oh << 5) | ow;
        aeoff[i] = (size_t)((n * 30 + oh) * 30 + ow) * 256 + uo;
        weoff[i] = (size_t)(oc0 + r) * 2304 + uo;
    }
    const int ldsa0 = t * 16;
    const int ldsw0 = 16384 + t * 16;

    const int lane = t & 63, wid = t >> 6;
    const int wm = (wid >> 1) << 6, woc = (wid & 1) << 6;
    const int lrow = lane & 15, lhi = lane >> 4;
    int aoffs[4][2], woffs[4][2];
    #pragma unroll
    for (int f = 0; f < 4; ++f)
        #pragma unroll
        for (int h = 0; h < 2; ++h) {
            int ra = wm + f * 16 + lrow;
            aoffs[f][h] = ra * 128 + (((lhi + (h << 2)) ^ (ra & 7)) << 4);
            int rw = woc + f * 16 + lrow;
            woffs[f][h] = 16384 + rw * 128 + (((lhi + (h << 2)) ^ (rw & 7)) << 4);
        }

    floatx4 acc[4][4];
    #pragma unroll
    for (int a = 0; a < 4; ++a)
        #pragma unroll
        for (int b = 0; b < 4; ++b) acc[a][b] = (floatx4){0.f, 0.f, 0.f, 0.f};

    for (int s = 0; s < 38; ++s) {
        if (s < 36) {
            int tap = s >> 2, chunk = s & 3;
            int kh = tap / 3, kw = tap % 3;
            size_t aoff = (size_t)(kh * 30 + kw) * 256 + chunk * 64;
            size_t woff = (size_t)s * 64;
            #pragma unroll
            for (int i = 0; i < 4; ++i) gload16(actpad + aeoff[i] + aoff, lds + ldsa0 + i * 4096);
            #pragma unroll
            for (int i = 0; i < 4; ++i) gload16(w2t + weoff[i] + woff, lds + ldsw0 + i * 4096);
        } else {
            int chunk = s - 36;
            #pragma unroll
            for (int i = 0; i < 4; ++i) {
                int n = pk[i] >> 10, oh = (pk[i] >> 5) & 31, ow = pk[i] & 31;
                gload16(xpad + (size_t)((n * 58 + 2 * oh + 1) * 58 + (2 * ow + 1)) * 128 + uo + chunk * 64,
                        lds + ldsa0 + i * 4096);
                int r = srow + 32 * i;
                gload16(wdst + (size_t)(oc0 + r) * 128 + uo + chunk * 64, lds + ldsw0 + i * 4096);
            }
        }
        __syncthreads();
        #pragma unroll
        for (int h = 0; h < 2; ++h) {
            short8 af[4], wf[4];
            #pragma unroll
            for (int f = 0; f < 4; ++f) af[f] = *(const short8*)(lds + aoffs[f][h]);
            #pragma unroll
            for (int f = 0; f < 4; ++f) wf[f] = *(const short8*)(lds + woffs[f][h]);
            #pragma unroll
            for (int fm = 0; fm < 4; ++fm)
                #pragma unroll
                for (int fo = 0; fo < 4; ++fo)
                    acc[fm][fo] = __builtin_amdgcn_mfma_f32_16x16x32_bf16(wf[fo], af[fm], acc[fm][fo], 0, 0, 0);
        }
        __syncthreads();
    }

    // epilogue: D rows = oc ((lane>>4)*4+reg), cols = m (lane&15); NCHW f32, 16 lanes = 64B contiguous
    #pragma unroll
    for (int fm = 0; fm < 4; ++fm) {
        int mcol = m0 + wm + fm * 16 + lrow;
        int n = mcol / 784, pix = mcol % 784;
        float* obase = out + (size_t)n * 200704 + pix;
        #pragma unroll
        for (int fo = 0; fo < 4; ++fo) {
            int ocb = oc0 + woc + fo * 16 + (lhi << 2);
            #pragma unroll
            for (int rg = 0; rg < 4; ++rg) {
                int oc = ocb + rg;
                float v = acc[fm][fo][rg] + b2[oc] + bds[oc];
                obase[(size_t)oc * 784] = fmaxf(v, 0.0f);
            }
        }
    }
}

extern "C" void kernel_launch(void* const* d_in, const int* in_sizes, int n_in,
                              void* d_out, int out_size, void* d_ws, size_t ws_size,
                              hipStream_t stream) {
    const float* x   = (const float*)d_in[0];
    const float* w1  = (const float*)d_in[1];
    const float* b1  = (const float*)d_in[2];
    const float* w2  = (const float*)d_in[3];
    const float* b2  = (const float*)d_in[4];
    const float* wds = (const float*)d_in[5];
    const float* bds = (const float*)d_in[6];
    float* out = (float*)d_out;

    char* ws = (char*)d_ws;
    bf16* xpad   = (bf16*)(ws + OFF_XPAD);
    bf16* actpad = (bf16*)(ws + OFF_ACTPAD);
    bf16* w1t    = (bf16*)(ws + OFF_W1T);
    bf16* w2t    = (bf16*)(ws + OFF_W2T);
    bf16* wdst   = (bf16*)(ws + OFF_WDST);

    // zero halos (ws is poisoned 0xAA before every timed call)
    hipMemsetAsync(xpad, 0, XPAD_BYTES, stream);
    hipMemsetAsync(actpad, 0, ACTPAD_BYTES, stream);

    wtrans_kernel<<<2304, 256, 0, stream>>>(w1, w2, wds, w1t, w2t, wdst);
    xpad_kernel<<<64 * 56, 256, 0, stream>>>(x, xpad);
    conv1_kernel<<<dim3(2, 392), 256, 0, stream>>>(xpad, w1t, b1, actpad);
    conv2_kernel<<<dim3(2, 392), 256, 0, stream>>>(actpad, xpad, w2t, wdst, b2, bds, out);
}

// Round 2
// 321.557 us; speedup vs baseline: 1.0687x; 1.0687x over previous
//
#include <hip/hip_runtime.h>
#include <hip/hip_bf16.h>

typedef short short8 __attribute__((ext_vector_type(8)));
typedef float floatx4 __attribute__((ext_vector_type(4)));
typedef __hip_bfloat16 bf16;

#define GLB(p) ((const __attribute__((address_space(1))) void*)(p))
#define LDSP(p) ((__attribute__((address_space(3))) void*)(p))

__device__ __forceinline__ void gload16(const bf16* g, char* l) {
    __builtin_amdgcn_global_load_lds(GLB(g), LDSP(l), 16, 0, 0);
}

#define VMCNT(n) asm volatile("s_waitcnt vmcnt(" #n ")" ::: "memory")
#define LGKM0()  asm volatile("s_waitcnt lgkmcnt(0)" ::: "memory")
#define BAR()    __builtin_amdgcn_s_barrier()

// ---- problem sizes ----
// x: (64,128,56,56) f32; out: (64,256,28,28) f32
// xpad:  [64][58][58][128] bf16 (halo=1, conv1 pad baked in)
// actpad:[64][30][30][256] bf16 (halo=1 for conv2 pad)
#define XPAD_BYTES   (64u*58*58*128*2)
#define ACTPAD_BYTES (64u*30*30*256*2)
#define OFF_XPAD   0
#define OFF_ACTPAD (XPAD_BYTES)
#define OFF_W1T    (OFF_ACTPAD + ACTPAD_BYTES)
#define OFF_W2T    (OFF_W1T + 1152u*256*2)
#define OFF_WDST   (OFF_W2T + 2304u*256*2)

// ---------------- weight transforms: OIHW f32 -> [oc][k] bf16, k=(kh*3+kw)*C+ic
__global__ void wtrans_kernel(const float* __restrict__ w1, const float* __restrict__ w2,
                              const float* __restrict__ wds,
                              bf16* __restrict__ w1t, bf16* __restrict__ w2t,
                              bf16* __restrict__ wdst) {
    int i = blockIdx.x * 256 + threadIdx.x;
    if (i < 256 * 1152) {
        int oc = i / 1152, k = i % 1152, tap = k >> 7, ic = k & 127;
        w1t[i] = __float2bfloat16(w1[(oc * 128 + ic) * 9 + tap]);
    }
    if (i < 256 * 2304) {
        int oc = i / 2304, k = i % 2304, tap = k >> 8, ic = k & 255;
        w2t[i] = __float2bfloat16(w2[(oc * 256 + ic) * 9 + tap]);
    }
    if (i < 256 * 128) {
        wdst[i] = __float2bfloat16(wds[i]); // already [oc][ic]
    }
}

// ---------------- zero ONLY the halos of xpad and actpad (replaces 85MB memsets)
__global__ void halo_zero_kernel(bf16* __restrict__ xpad, bf16* __restrict__ actpad) {
    int i = blockIdx.x * 256 + threadIdx.x;
    uint4 z; z.x = z.y = z.z = z.w = 0;
    const int n0 = 64 * 2 * 58 * 16;       // xpad rows h=0,57
    const int n1 = n0 + 64 * 56 * 2 * 16;  // xpad cols w=0,57 (h=1..56)
    const int n2 = n1 + 64 * 2 * 30 * 32;  // actpad rows h=0,29
    const int n3 = n2 + 64 * 28 * 2 * 32;  // actpad cols w=0,29 (h=1..28)
    if (i < n0) {
        int g = i & 15, w = (i >> 4) % 58, q = (i >> 4) / 58;
        int n = q >> 1, h = (q & 1) ? 57 : 0;
        *(uint4*)(xpad + ((size_t)((n * 58 + h) * 58 + w)) * 128 + g * 8) = z;
    } else if (i < n1) {
        int j = i - n0;
        int g = j & 15, q = j >> 4;
        int w = (q & 1) ? 57 : 0, h = (q >> 1) % 56 + 1, n = (q >> 1) / 56;
        *(uint4*)(xpad + ((size_t)((n * 58 + h) * 58 + w)) * 128 + g * 8) = z;
    } else if (i < n2) {
        int j = i - n1;
        int g = j & 31, w = (j >> 5) % 30, q = (j >> 5) / 30;
        int n = q >> 1, h = (q & 1) ? 29 : 0;
        *(uint4*)(actpad + ((size_t)((n * 30 + h) * 30 + w)) * 256 + g * 8) = z;
    } else if (i < n3) {
        int j = i - n2;
        int g = j & 31, q = j >> 5;
        int w = (q & 1) ? 29 : 0, h = (q >> 1) % 28 + 1, n = (q >> 1) / 28;
        *(uint4*)(actpad + ((size_t)((n * 30 + h) * 30 + w)) * 256 + g * 8) = z;
    }
}

// ---------------- x: NCHW f32 -> xpad NHWC bf16 (interior only; halo zeroed separately)
__global__ void xpad_kernel(const float* __restrict__ x, bf16* __restrict__ xpad) {
    int bid = blockIdx.x;             // 64*56 blocks: one (n,h) row each
    int n = bid / 56, h = bid % 56;
    __shared__ float tile[128 * 57];
    const float* src = x + ((size_t)n * 128) * 3136 + h * 56;
    for (int e = threadIdx.x; e < 128 * 56; e += 256) {
        int c = e / 56, w = e % 56;
        tile[c * 57 + w] = src[(size_t)c * 3136 + w];
    }
    __syncthreads();
    bf16* dst = xpad + ((size_t)(n * 58 + h + 1) * 58 + 1) * 128;
    for (int e = threadIdx.x; e < 56 * 16; e += 256) {
        int w = e / 16, g = e % 16;
        union { bf16 b[8]; uint4 v; } o;
        #pragma unroll
        for (int j = 0; j < 8; ++j)
            o.b[j] = __float2bfloat16(tile[(g * 8 + j) * 57 + w]);
        *(uint4*)(dst + (size_t)w * 128 + g * 8) = o.v;
    }
}

// =====================================================================
// conv1: 3x3 s2 p1 + b1 + relu -> actpad (bf16 NHWC padded)
// 256(m) x 256(oc) tile, K=1152 (36 tiles of 32). 512 thr, 8 waves (2m x 4oc).
// Pipelined: 4 LDS slots, stage 3 tiles ahead, counted vmcnt.
// =====================================================================
__global__ __launch_bounds__(512, 2) void conv1_kernel(
    const bf16* __restrict__ xpad, const bf16* __restrict__ w1t,
    const float* __restrict__ b1, bf16* __restrict__ actpad)
{
    __shared__ __align__(16) char lds[131072];   // 4 slots x (A 16K + B 16K)
    const int t = threadIdx.x;
    const int m0 = blockIdx.x * 256;

    // staging addresses
    const int unit = t & 3, srow = t >> 2;
    int xb[2], wb[2];
    #pragma unroll
    for (int r = 0; r < 2; ++r) {
        int m = m0 + r * 128 + srow;
        int n = m / 784, pix = m % 784, oh = pix / 28, ow = pix % 28;
        xb[r] = ((n * 58 + 2 * oh) * 58 + 2 * ow) * 128 + unit * 8;
        wb[r] = (r * 128 + srow) * 1152 + unit * 8;
    }
    char* const ldsA = lds + t * 16;
    char* const ldsB = lds + 16384 + t * 16;

    auto STAGE_A = [&](int kt, int slot) {
        int tap = kt >> 2, chunk = kt & 3;
        int kh = (tap * 11) >> 5, kw = tap - kh * 3;
        int toff = (kh * 58 + kw) * 128 + chunk * 32;
        gload16(xpad + xb[0] + toff, ldsA + slot * 32768);
        gload16(xpad + xb[1] + toff, ldsA + slot * 32768 + 8192);
    };
    auto STAGE_B = [&](int kt, int slot) {
        gload16(w1t + wb[0] + kt * 32, ldsB + slot * 32768);
        gload16(w1t + wb[1] + kt * 32, ldsB + slot * 32768 + 8192);
    };

    // fragment read offsets
    const int lane = t & 63, wid = t >> 6;
    const int wm = (wid >> 2) << 7, woc = (wid & 3) << 6;
    const int lr = lane & 15, kg = lane >> 4;
    int aoff[8], boff[4];
    #pragma unroll
    for (int f = 0; f < 8; ++f) aoff[f] = (wm + f * 16 + lr) * 64 + kg * 16;
    #pragma unroll
    for (int g = 0; g < 4; ++g) boff[g] = 16384 + (woc + g * 16 + lr) * 64 + kg * 16;

    floatx4 acc[8][4];
    #pragma unroll
    for (int a = 0; a < 8; ++a)
        #pragma unroll
        for (int b = 0; b < 4; ++b) acc[a][b] = (floatx4){0.f, 0.f, 0.f, 0.f};

    // prologue: tiles 0,1,2
    STAGE_A(0, 0); STAGE_B(0, 0);
    STAGE_A(1, 1); STAGE_B(1, 1);
    STAGE_A(2, 2); STAGE_B(2, 2);
    VMCNT(8); BAR();

    #pragma unroll 4
    for (int kt = 0; kt < 36; ++kt) {
        const int cs = kt & 3;
        const char* base = lds + (cs << 15);
        short8 wfr[4];
        #pragma unroll
        for (int g = 0; g < 4; ++g) wfr[g] = *(const short8*)(base + boff[g]);
        {   // phase 0: m-frags 0..3
            short8 afr[4];
            #pragma unroll
            for (int f = 0; f < 4; ++f) afr[f] = *(const short8*)(base + aoff[f]);
            if (kt + 3 < 36) STAGE_A(kt + 3, (kt + 3) & 3);
            BAR(); LGKM0();
            __builtin_amdgcn_s_setprio(1);
            #pragma unroll
            for (int f = 0; f < 4; ++f)
                #pragma unroll
                for (int fo = 0; fo < 4; ++fo)
                    acc[f][fo] = __builtin_amdgcn_mfma_f32_16x16x32_bf16(afr[f], wfr[fo], acc[f][fo], 0, 0, 0);
            __builtin_amdgcn_s_setprio(0);
            BAR();
        }
        {   // phase 1: m-frags 4..7
            short8 afr[4];
            #pragma unroll
            for (int f = 0; f < 4; ++f) afr[f] = *(const short8*)(base + aoff[4 + f]);
            if (kt + 3 < 36) STAGE_B(kt + 3, (kt + 3) & 3);
            BAR(); LGKM0();
            __builtin_amdgcn_s_setprio(1);
            #pragma unroll
            for (int f = 0; f < 4; ++f)
                #pragma unroll
                for (int fo = 0; fo < 4; ++fo)
                    acc[4 + f][fo] = __builtin_amdgcn_mfma_f32_16x16x32_bf16(afr[f], wfr[fo], acc[4 + f][fo], 0, 0, 0);
            __builtin_amdgcn_s_setprio(0);
            int rem = 35 - kt;
            if (rem >= 3) { VMCNT(8); }
            else if (rem == 2) { VMCNT(4); }
            else if (rem == 1) { VMCNT(0); }
            BAR();
        }
    }

    // epilogue: D rows=m (kg*4+rg), cols=oc (lr)
    #pragma unroll
    for (int fm = 0; fm < 8; ++fm) {
        #pragma unroll
        for (int rg = 0; rg < 4; ++rg) {
            int m = m0 + wm + fm * 16 + (kg << 2) + rg;
            int n = m / 784, pix = m % 784;
            int oh = pix / 28, ow = pix % 28;
            bf16* dst = actpad + ((size_t)(n * 30 + oh + 1) * 30 + (ow + 1)) * 256;
            #pragma unroll
            for (int fo = 0; fo < 4; ++fo) {
                int oc = woc + fo * 16 + lr;
                float v = acc[fm][fo][rg] + b1[oc];
                dst[oc] = __float2bfloat16(fmaxf(v, 0.0f));
            }
        }
    }
}

// =====================================================================
// conv2: 3x3 s1 p1 over actpad + b2 + (1x1 s2 shortcut + bds) + relu -> out NCHW f32
// 256(m) x 256(oc) tile, K = 2304 + 128 (76 tiles of 32). Same pipeline.
// =====================================================================
__global__ __launch_bounds__(512, 2) void conv2_kernel(
    const bf16* __restrict__ actpad, const bf16* __restrict__ xpad,
    const bf16* __restrict__ w2t, const bf16* __restrict__ wdst,
    const float* __restrict__ b2, const float* __restrict__ bds,
    float* __restrict__ out)
{
    __shared__ __align__(16) char lds[131072];
    const int t = threadIdx.x;
    const int m0 = blockIdx.x * 256;

    const int unit = t & 3, srow = t >> 2;
    int ab[2], xb[2], wb[2], db[2];
    #pragma unroll
    for (int r = 0; r < 2; ++r) {
        int m = m0 + r * 128 + srow;
        int n = m / 784, pix = m % 784, oh = pix / 28, ow = pix % 28;
        ab[r] = ((n * 30 + oh) * 30 + ow) * 256 + unit * 8;
        xb[r] = ((n * 58 + 2 * oh + 1) * 58 + (2 * ow + 1)) * 128 + unit * 8;
        wb[r] = (r * 128 + srow) * 2304 + unit * 8;
        db[r] = (r * 128 + srow) * 128 + unit * 8;
    }
    char* const ldsA = lds + t * 16;
    char* const ldsB = lds + 16384 + t * 16;

    auto STAGE_A = [&](int kt, int slot) {
        if (kt < 72) {
            int tap = kt >> 3, chunk = kt & 7;
            int kh = (tap * 11) >> 5, kw = tap - kh * 3;
            int toff = (kh * 30 + kw) * 256 + chunk * 32;
            gload16(actpad + ab[0] + toff, ldsA + slot * 32768);
            gload16(actpad + ab[1] + toff, ldsA + slot * 32768 + 8192);
        } else {
            int chunk = kt - 72;
            gload16(xpad + xb[0] + chunk * 32, ldsA + slot * 32768);
            gload16(xpad + xb[1] + chunk * 32, ldsA + slot * 32768 + 8192);
        }
    };
    auto STAGE_B = [&](int kt, int slot) {
        if (kt < 72) {
            gload16(w2t + wb[0] + kt * 32, ldsB + slot * 32768);
            gload16(w2t + wb[1] + kt * 32, ldsB + slot * 32768 + 8192);
        } else {
            int chunk = kt - 72;
            gload16(wdst + db[0] + chunk * 32, ldsB + slot * 32768);
            gload16(wdst + db[1] + chunk * 32, ldsB + slot * 32768 + 8192);
        }
    };

    const int lane = t & 63, wid = t >> 6;
    const int wm = (wid >> 2) << 7, woc = (wid & 3) << 6;
    const int lr = lane & 15, kg = lane >> 4;
    int aoff[8], boff[4];
    #pragma unroll
    for (int f = 0; f < 8; ++f) aoff[f] = (wm + f * 16 + lr) * 64 + kg * 16;
    #pragma unroll
    for (int g = 0; g < 4; ++g) boff[g] = 16384 + (woc + g * 16 + lr) * 64 + kg * 16;

    floatx4 acc[8][4];
    #pragma unroll
    for (int a = 0; a < 8; ++a)
        #pragma unroll
        for (int b = 0; b < 4; ++b) acc[a][b] = (floatx4){0.f, 0.f, 0.f, 0.f};

    STAGE_A(0, 0); STAGE_B(0, 0);
    STAGE_A(1, 1); STAGE_B(1, 1);
    STAGE_A(2, 2); STAGE_B(2, 2);
    VMCNT(8); BAR();

    #pragma unroll 4
    for (int kt = 0; kt < 76; ++kt) {
        const int cs = kt & 3;
        const char* base = lds + (cs << 15);
        short8 wfr[4];
        #pragma unroll
        for (int g = 0; g < 4; ++g) wfr[g] = *(const short8*)(base + boff[g]);
        {   // phase 0
            short8 afr[4];
            #pragma unroll
            for (int f = 0; f < 4; ++f) afr[f] = *(const short8*)(base + aoff[f]);
            if (kt + 3 < 76) STAGE_A(kt + 3, (kt + 3) & 3);
            BAR(); LGKM0();
            __builtin_amdgcn_s_setprio(1);
            #pragma unroll
            for (int f = 0; f < 4; ++f)
                #pragma unroll
                for (int fo = 0; fo < 4; ++fo)
                    acc[f][fo] = __builtin_amdgcn_mfma_f32_16x16x32_bf16(wfr[fo], afr[f], acc[f][fo], 0, 0, 0);
            __builtin_amdgcn_s_setprio(0);
            BAR();
        }
        {   // phase 1
            short8 afr[4];
            #pragma unroll
            for (int f = 0; f < 4; ++f) afr[f] = *(const short8*)(base + aoff[4 + f]);
            if (kt + 3 < 76) STAGE_B(kt + 3, (kt + 3) & 3);
            BAR(); LGKM0();
            __builtin_amdgcn_s_setprio(1);
            #pragma unroll
            for (int f = 0; f < 4; ++f)
                #pragma unroll
                for (int fo = 0; fo < 4; ++fo)
                    acc[4 + f][fo] = __builtin_amdgcn_mfma_f32_16x16x32_bf16(wfr[fo], afr[f], acc[4 + f][fo], 0, 0, 0);
            __builtin_amdgcn_s_setprio(0);
            int rem = 75 - kt;
            if (rem >= 3) { VMCNT(8); }
            else if (rem == 2) { VMCNT(4); }
            else if (rem == 1) { VMCNT(0); }
            BAR();
        }
    }

    // epilogue: D rows=oc (kg*4+rg), cols=m (lr); NCHW f32
    #pragma unroll
    for (int fm = 0; fm < 8; ++fm) {
        int mcol = m0 + wm + fm * 16 + lr;
        int n = mcol / 784, pix = mcol % 784;
        float* obase = out + (size_t)n * 200704 + pix;
        #pragma unroll
        for (int fo = 0; fo < 4; ++fo) {
            int ocb = woc + fo * 16 + (kg << 2);
            #pragma unroll
            for (int rg = 0; rg < 4; ++rg) {
                int oc = ocb + rg;
                float v = acc[fm][fo][rg] + b2[oc] + bds[oc];
                obase[(size_t)oc * 784] = fmaxf(v, 0.0f);
            }
        }
    }
}

extern "C" void kernel_launch(void* const* d_in, const int* in_sizes, int n_in,
                              void* d_out, int out_size, void* d_ws, size_t ws_size,
                              hipStream_t stream) {
    const float* x   = (const float*)d_in[0];
    const float* w1  = (const float*)d_in[1];
    const float* b1  = (const float*)d_in[2];
    const float* w2  = (const float*)d_in[3];
    const float* b2  = (const float*)d_in[4];
    const float* wds = (const float*)d_in[5];
    const float* bds = (const float*)d_in[6];
    float* out = (float*)d_out;

    char* ws = (char*)d_ws;
    bf16* xpad   = (bf16*)(ws + OFF_XPAD);
    bf16* actpad = (bf16*)(ws + OFF_ACTPAD);
    bf16* w1t    = (bf16*)(ws + OFF_W1T);
    bf16* w2t    = (bf16*)(ws + OFF_W2T);
    bf16* wdst   = (bf16*)(ws + OFF_WDST);

    halo_zero_kernel<<<1840, 256, 0, stream>>>(xpad, actpad);
    wtrans_kernel<<<2304, 256, 0, stream>>>(w1, w2, wds, w1t, w2t, wdst);
    xpad_kernel<<<64 * 56, 256, 0, stream>>>(x, xpad);
    conv1_kernel<<<196, 512, 0, stream>>>(xpad, w1t, b1, actpad);
    conv2_kernel<<<196, 512, 0, stream>>>(actpad, xpad, w2t, wdst, b2, bds, out);
}

// Round 3
// 316.145 us; speedup vs baseline: 1.0870x; 1.0171x over previous
//
#include <hip/hip_runtime.h>
#include <hip/hip_bf16.h>

typedef short short8 __attribute__((ext_vector_type(8)));
typedef float floatx4 __attribute__((ext_vector_type(4)));
typedef __hip_bfloat16 bf16;

#define GLB(p) ((const __attribute__((address_space(1))) void*)(p))
#define LDSP(p) ((__attribute__((address_space(3))) void*)(p))

__device__ __forceinline__ void gload16(const bf16* g, char* l) {
    __builtin_amdgcn_global_load_lds(GLB(g), LDSP(l), 16, 0, 0);
}

#define VMCNT(n) asm volatile("s_waitcnt vmcnt(" #n ")" ::: "memory")
#define BAR()    __builtin_amdgcn_s_barrier()

// ---- problem sizes ----
// x: (64,128,56,56) f32; out: (64,256,28,28) f32
// xpad:  [64][58][58][128] bf16 (halo=1, conv1 pad baked in)
// actpad:[64][30][30][256] bf16 (halo=1 for conv2 pad)
#define XPAD_BYTES   (64u*58*58*128*2)
#define ACTPAD_BYTES (64u*30*30*256*2)
#define OFF_XPAD   0
#define OFF_ACTPAD (XPAD_BYTES)
#define OFF_W1T    (OFF_ACTPAD + ACTPAD_BYTES)
#define OFF_W2T    (OFF_W1T + 1152u*256*2)
#define OFF_WDST   (OFF_W2T + 2304u*256*2)

// ---------------- weight transforms: OIHW f32 -> [oc][k] bf16, k=(kh*3+kw)*C+ic
__global__ void wtrans_kernel(const float* __restrict__ w1, const float* __restrict__ w2,
                              const float* __restrict__ wds,
                              bf16* __restrict__ w1t, bf16* __restrict__ w2t,
                              bf16* __restrict__ wdst) {
    int i = blockIdx.x * 256 + threadIdx.x;
    if (i < 256 * 1152) {
        int oc = i / 1152, k = i % 1152, tap = k >> 7, ic = k & 127;
        w1t[i] = __float2bfloat16(w1[(oc * 128 + ic) * 9 + tap]);
    }
    if (i < 256 * 2304) {
        int oc = i / 2304, k = i % 2304, tap = k >> 8, ic = k & 255;
        w2t[i] = __float2bfloat16(w2[(oc * 256 + ic) * 9 + tap]);
    }
    if (i < 256 * 128) {
        wdst[i] = __float2bfloat16(wds[i]); // already [oc][ic]
    }
}

// ---------------- zero ONLY the halos of xpad and actpad
__global__ void halo_zero_kernel(bf16* __restrict__ xpad, bf16* __restrict__ actpad) {
    int i = blockIdx.x * 256 + threadIdx.x;
    uint4 z; z.x = z.y = z.z = z.w = 0;
    const int n0 = 64 * 2 * 58 * 16;       // xpad rows h=0,57
    const int n1 = n0 + 64 * 56 * 2 * 16;  // xpad cols w=0,57 (h=1..56)
    const int n2 = n1 + 64 * 2 * 30 * 32;  // actpad rows h=0,29
    const int n3 = n2 + 64 * 28 * 2 * 32;  // actpad cols w=0,29 (h=1..28)
    if (i < n0) {
        int g = i & 15, w = (i >> 4) % 58, q = (i >> 4) / 58;
        int n = q >> 1, h = (q & 1) ? 57 : 0;
        *(uint4*)(xpad + ((size_t)((n * 58 + h) * 58 + w)) * 128 + g * 8) = z;
    } else if (i < n1) {
        int j = i - n0;
        int g = j & 15, q = j >> 4;
        int w = (q & 1) ? 57 : 0, h = (q >> 1) % 56 + 1, n = (q >> 1) / 56;
        *(uint4*)(xpad + ((size_t)((n * 58 + h) * 58 + w)) * 128 + g * 8) = z;
    } else if (i < n2) {
        int j = i - n1;
        int g = j & 31, w = (j >> 5) % 30, q = (j >> 5) / 30;
        int n = q >> 1, h = (q & 1) ? 29 : 0;
        *(uint4*)(actpad + ((size_t)((n * 30 + h) * 30 + w)) * 256 + g * 8) = z;
    } else if (i < n3) {
        int j = i - n2;
        int g = j & 31, q = j >> 5;
        int w = (q & 1) ? 29 : 0, h = (q >> 1) % 28 + 1, n = (q >> 1) / 28;
        *(uint4*)(actpad + ((size_t)((n * 30 + h) * 30 + w)) * 256 + g * 8) = z;
    }
}

// ---------------- x: NCHW f32 -> xpad NHWC bf16 (interior only)
__global__ void xpad_kernel(const float* __restrict__ x, bf16* __restrict__ xpad) {
    int bid = blockIdx.x;             // 64*56 blocks: one (n,h) row each
    int n = bid / 56, h = bid % 56;
    __shared__ float tile[128 * 57];
    const float* src = x + ((size_t)n * 128) * 3136 + h * 56;
    for (int e = threadIdx.x; e < 128 * 56; e += 256) {
        int c = e / 56, w = e % 56;
        tile[c * 57 + w] = src[(size_t)c * 3136 + w];
    }
    __syncthreads();
    bf16* dst = xpad + ((size_t)(n * 58 + h + 1) * 58 + 1) * 128;
    for (int e = threadIdx.x; e < 56 * 16; e += 256) {
        int w = e / 16, g = e % 16;
        union { bf16 b[8]; uint4 v; } o;
        #pragma unroll
        for (int j = 0; j < 8; ++j)
            o.b[j] = __float2bfloat16(tile[(g * 8 + j) * 57 + w]);
        *(uint4*)(dst + (size_t)w * 128 + g * 8) = o.v;
    }
}

// =====================================================================
// conv1: 3x3 s2 p1 + b1 + relu -> actpad (bf16 NHWC padded)
// 256(m) x 256(oc), K=1152 (36 kt of 32). 512 thr, 8 waves (2m x 4oc).
// 4 LDS slots, stage 3 ahead, counted vmcnt, T2 XOR swizzle (unit^((row>>1)&3)).
// =====================================================================
__global__ __launch_bounds__(512, 2) void conv1_kernel(
    const bf16* __restrict__ xpad, const bf16* __restrict__ w1t,
    const float* __restrict__ b1, bf16* __restrict__ actpad)
{
    __shared__ __align__(16) char lds[131072];   // 4 slots x (A 16K + B 16K)
    const int t = threadIdx.x;
    const int m0 = blockIdx.x * 256;

    // staging: thread t owns LDS unit (row=t>>2, unit=t&3); fetch swizzled slot
    const int srow = t >> 2;
    const int su = (t & 3) ^ ((srow >> 1) & 3);   // source slot (swizzle)
    int xb[2], wb[2];
    #pragma unroll
    for (int r = 0; r < 2; ++r) {
        int m = m0 + r * 128 + srow;
        int n = m / 784, pix = m % 784, oh = pix / 28, ow = pix % 28;
        xb[r] = ((n * 58 + 2 * oh) * 58 + 2 * ow) * 128 + su * 8;
        wb[r] = (r * 128 + srow) * 1152 + su * 8;
    }
    char* const ldsA = lds + t * 16;
    char* const ldsB = lds + 16384 + t * 16;

    auto STAGE_A = [&](int kt, int slot) {
        int tap = kt >> 2, chunk = kt & 3;
        int kh = (tap * 11) >> 5, kw = tap - kh * 3;
        int toff = (kh * 58 + kw) * 128 + chunk * 32;
        gload16(xpad + xb[0] + toff, ldsA + slot * 32768);
        gload16(xpad + xb[1] + toff, ldsA + slot * 32768 + 8192);
    };
    auto STAGE_B = [&](int kt, int slot) {
        gload16(w1t + wb[0] + kt * 32, ldsB + slot * 32768);
        gload16(w1t + wb[1] + kt * 32, ldsB + slot * 32768 + 8192);
    };

    // fragment read offsets (swizzled to match)
    const int lane = t & 63, wid = t >> 6;
    const int wm = (wid >> 2) << 7, woc = (wid & 3) << 6;
    const int lr = lane & 15, kg = lane >> 4;
    const int ks = (kg ^ ((lr >> 1) & 3)) << 4;   // swizzled 16B slot within row
    int aoff[8], boff[4];
    #pragma unroll
    for (int f = 0; f < 8; ++f) aoff[f] = (wm + f * 16 + lr) * 64 + ks;
    #pragma unroll
    for (int g = 0; g < 4; ++g) boff[g] = 16384 + (woc + g * 16 + lr) * 64 + ks;

    floatx4 acc[8][4];
    #pragma unroll
    for (int a = 0; a < 8; ++a)
        #pragma unroll
        for (int b = 0; b < 4; ++b) acc[a][b] = (floatx4){0.f, 0.f, 0.f, 0.f};

    STAGE_A(0, 0); STAGE_B(0, 0);
    STAGE_A(1, 1); STAGE_B(1, 1);
    STAGE_A(2, 2); STAGE_B(2, 2);
    VMCNT(8); BAR();

    #pragma unroll 4
    for (int kt = 0; kt < 36; ++kt) {
        const int cs = kt & 3;
        const char* base = lds + (cs << 15);
        short8 wfr[4], afrA[4], afrB[4];
        #pragma unroll
        for (int g = 0; g < 4; ++g) wfr[g] = *(const short8*)(base + boff[g]);
        #pragma unroll
        for (int f = 0; f < 4; ++f) afrA[f] = *(const short8*)(base + aoff[f]);
        #pragma unroll
        for (int f = 0; f < 4; ++f) afrB[f] = *(const short8*)(base + aoff[4 + f]);
        if (kt + 3 < 36) STAGE_A(kt + 3, (kt + 3) & 3);
        BAR();
        __builtin_amdgcn_s_setprio(1);
        #pragma unroll
        for (int f = 0; f < 4; ++f)
            #pragma unroll
            for (int fo = 0; fo < 4; ++fo)
                acc[f][fo] = __builtin_amdgcn_mfma_f32_16x16x32_bf16(afrA[f], wfr[fo], acc[f][fo], 0, 0, 0);
        __builtin_amdgcn_s_setprio(0);
        BAR();
        if (kt + 3 < 36) STAGE_B(kt + 3, (kt + 3) & 3);
        __builtin_amdgcn_s_setprio(1);
        #pragma unroll
        for (int f = 0; f < 4; ++f)
            #pragma unroll
            for (int fo = 0; fo < 4; ++fo)
                acc[4 + f][fo] = __builtin_amdgcn_mfma_f32_16x16x32_bf16(afrB[f], wfr[fo], acc[4 + f][fo], 0, 0, 0);
        __builtin_amdgcn_s_setprio(0);
        int rem = 35 - kt;
        if (rem >= 3) { VMCNT(8); }
        else if (rem == 2) { VMCNT(4); }
        else if (rem == 1) { VMCNT(0); }
        BAR();
    }

    // epilogue: D rows=m (kg*4+rg), cols=oc (lr)
    #pragma unroll
    for (int fm = 0; fm < 8; ++fm) {
        #pragma unroll
        for (int rg = 0; rg < 4; ++rg) {
            int m = m0 + wm + fm * 16 + (kg << 2) + rg;
            int n = m / 784, pix = m % 784;
            int oh = pix / 28, ow = pix % 28;
            bf16* dst = actpad + ((size_t)(n * 30 + oh + 1) * 30 + (ow + 1)) * 256;
            #pragma unroll
            for (int fo = 0; fo < 4; ++fo) {
                int oc = woc + fo * 16 + lr;
                float v = acc[fm][fo][rg] + b1[oc];
                dst[oc] = __float2bfloat16(fmaxf(v, 0.0f));
            }
        }
    }
}

// =====================================================================
// conv2: 3x3 s1 p1 over actpad + b2 + (1x1 s2 shortcut + bds) + relu -> out NCHW f32
// K = 2304 + 128 (76 kt of 32). Same structure.
// =====================================================================
__global__ __launch_bounds__(512, 2) void conv2_kernel(
    const bf16* __restrict__ actpad, const bf16* __restrict__ xpad,
    const bf16* __restrict__ w2t, const bf16* __restrict__ wdst,
    const float* __restrict__ b2, const float* __restrict__ bds,
    float* __restrict__ out)
{
    __shared__ __align__(16) char lds[131072];
    const int t = threadIdx.x;
    const int m0 = blockIdx.x * 256;

    const int srow = t >> 2;
    const int su = (t & 3) ^ ((srow >> 1) & 3);
    int ab[2], xb[2], wb[2], db[2];
    #pragma unroll
    for (int r = 0; r < 2; ++r) {
        int m = m0 + r * 128 + srow;
        int n = m / 784, pix = m % 784, oh = pix / 28, ow = pix % 28;
        ab[r] = ((n * 30 + oh) * 30 + ow) * 256 + su * 8;
        xb[r] = ((n * 58 + 2 * oh + 1) * 58 + (2 * ow + 1)) * 128 + su * 8;
        wb[r] = (r * 128 + srow) * 2304 + su * 8;
        db[r] = (r * 128 + srow) * 128 + su * 8;
    }
    char* const ldsA = lds + t * 16;
    char* const ldsB = lds + 16384 + t * 16;

    auto STAGE_A = [&](int kt, int slot) {
        if (kt < 72) {
            int tap = kt >> 3, chunk = kt & 7;
            int kh = (tap * 11) >> 5, kw = tap - kh * 3;
            int toff = (kh * 30 + kw) * 256 + chunk * 32;
            gload16(actpad + ab[0] + toff, ldsA + slot * 32768);
            gload16(actpad + ab[1] + toff, ldsA + slot * 32768 + 8192);
        } else {
            int chunk = kt - 72;
            gload16(xpad + xb[0] + chunk * 32, ldsA + slot * 32768);
            gload16(xpad + xb[1] + chunk * 32, ldsA + slot * 32768 + 8192);
        }
    };
    auto STAGE_B = [&](int kt, int slot) {
        if (kt < 72) {
            gload16(w2t + wb[0] + kt * 32, ldsB + slot * 32768);
            gload16(w2t + wb[1] + kt * 32, ldsB + slot * 32768 + 8192);
        } else {
            int chunk = kt - 72;
            gload16(wdst + db[0] + chunk * 32, ldsB + slot * 32768);
            gload16(wdst + db[1] + chunk * 32, ldsB + slot * 32768 + 8192);
        }
    };

    const int lane = t & 63, wid = t >> 6;
    const int wm = (wid >> 2) << 7, woc = (wid & 3) << 6;
    const int lr = lane & 15, kg = lane >> 4;
    const int ks = (kg ^ ((lr >> 1) & 3)) << 4;
    int aoff[8], boff[4];
    #pragma unroll
    for (int f = 0; f < 8; ++f) aoff[f] = (wm + f * 16 + lr) * 64 + ks;
    #pragma unroll
    for (int g = 0; g < 4; ++g) boff[g] = 16384 + (woc + g * 16 + lr) * 64 + ks;

    floatx4 acc[8][4];
    #pragma unroll
    for (int a = 0; a < 8; ++a)
        #pragma unroll
        for (int b = 0; b < 4; ++b) acc[a][b] = (floatx4){0.f, 0.f, 0.f, 0.f};

    STAGE_A(0, 0); STAGE_B(0, 0);
    STAGE_A(1, 1); STAGE_B(1, 1);
    STAGE_A(2, 2); STAGE_B(2, 2);
    VMCNT(8); BAR();

    #pragma unroll 4
    for (int kt = 0; kt < 76; ++kt) {
        const int cs = kt & 3;
        const char* base = lds + (cs << 15);
        short8 wfr[4], afrA[4], afrB[4];
        #pragma unroll
        for (int g = 0; g < 4; ++g) wfr[g] = *(const short8*)(base + boff[g]);
        #pragma unroll
        for (int f = 0; f < 4; ++f) afrA[f] = *(const short8*)(base + aoff[f]);
        #pragma unroll
        for (int f = 0; f < 4; ++f) afrB[f] = *(const short8*)(base + aoff[4 + f]);
        if (kt + 3 < 76) STAGE_A(kt + 3, (kt + 3) & 3);
        BAR();
        __builtin_amdgcn_s_setprio(1);
        #pragma unroll
        for (int f = 0; f < 4; ++f)
            #pragma unroll
            for (int fo = 0; fo < 4; ++fo)
                acc[f][fo] = __builtin_amdgcn_mfma_f32_16x16x32_bf16(wfr[fo], afrA[f], acc[f][fo], 0, 0, 0);
        __builtin_amdgcn_s_setprio(0);
        BAR();
        if (kt + 3 < 76) STAGE_B(kt + 3, (kt + 3) & 3);
        __builtin_amdgcn_s_setprio(1);
        #pragma unroll
        for (int f = 0; f < 4; ++f)
            #pragma unroll
            for (int fo = 0; fo < 4; ++fo)
                acc[4 + f][fo] = __builtin_amdgcn_mfma_f32_16x16x32_bf16(wfr[fo], afrB[f], acc[4 + f][fo], 0, 0, 0);
        __builtin_amdgcn_s_setprio(0);
        int rem = 75 - kt;
        if (rem >= 3) { VMCNT(8); }
        else if (rem == 2) { VMCNT(4); }
        else if (rem == 1) { VMCNT(0); }
        BAR();
    }

    // epilogue: D rows=oc (kg*4+rg), cols=m (lr); NCHW f32
    #pragma unroll
    for (int fm = 0; fm < 8; ++fm) {
        int mcol = m0 + wm + fm * 16 + lr;
        int n = mcol / 784, pix = mcol % 784;
        float* obase = out + (size_t)n * 200704 + pix;
        #pragma unroll
        for (int fo = 0; fo < 4; ++fo) {
            int ocb = woc + fo * 16 + (kg << 2);
            #pragma unroll
            for (int rg = 0; rg < 4; ++rg) {
                int oc = ocb + rg;
                float v = acc[fm][fo][rg] + b2[oc] + bds[oc];
                obase[(size_t)oc * 784] = fmaxf(v, 0.0f);
            }
        }
    }
}

extern "C" void kernel_launch(void* const* d_in, const int* in_sizes, int n_in,
                              void* d_out, int out_size, void* d_ws, size_t ws_size,
                              hipStream_t stream) {
    const float* x   = (const float*)d_in[0];
    const float* w1  = (const float*)d_in[1];
    const float* b1  = (const float*)d_in[2];
    const float* w2  = (const float*)d_in[3];
    const float* b2  = (const float*)d_in[4];
    const float* wds = (const float*)d_in[5];
    const float* bds = (const float*)d_in[6];
    float* out = (float*)d_out;

    char* ws = (char*)d_ws;
    bf16* xpad   = (bf16*)(ws + OFF_XPAD);
    bf16* actpad = (bf16*)(ws + OFF_ACTPAD);
    bf16* w1t    = (bf16*)(ws + OFF_W1T);
    bf16* w2t    = (bf16*)(ws + OFF_W2T);
    bf16* wdst   = (bf16*)(ws + OFF_WDST);

    halo_zero_kernel<<<1840, 256, 0, stream>>>(xpad, actpad);
    wtrans_kernel<<<2304, 256, 0, stream>>>(w1, w2, wds, w1t, w2t, wdst);
    xpad_kernel<<<64 * 56, 256, 0, stream>>>(x, xpad);
    conv1_kernel<<<196, 512, 0, stream>>>(xpad, w1t, b1, actpad);
    conv2_kernel<<<196, 512, 0, stream>>>(actpad, xpad, w2t, wdst, b2, bds, out);
}